// Round 9
// baseline (2307.243 us; speedup 1.0000x reference)
//
#include <hip/hip_runtime.h>
#include <math.h>

#define Bc 16
#define Nc 1024
#define Fc 256
#define Hc 8
#define Kc 512
#define DOUTc 256
#define EPSc 1e-8f

typedef short v8s __attribute__((ext_vector_type(8)));
typedef float v4f __attribute__((ext_vector_type(4)));

__device__ __forceinline__ float waveReduceSum(float v) {
    v += __shfl_xor(v, 32); v += __shfl_xor(v, 16); v += __shfl_xor(v, 8);
    v += __shfl_xor(v, 4);  v += __shfl_xor(v, 2);  v += __shfl_xor(v, 1);
    return v;
}

__device__ __forceinline__ unsigned short f2bf(float f) {
    unsigned int u = __float_as_uint(f);
    u = (u + 0x7fffu + ((u >> 16) & 1u)) >> 16;   // RNE
    return (unsigned short)u;
}

// LDS-only barrier: drains lgkmcnt, leaves global loads in flight.
__device__ __forceinline__ void lds_barrier() {
    __builtin_amdgcn_s_waitcnt(0xC07F);
    __builtin_amdgcn_s_barrier();
}

// async global->LDS, 16 B per lane: LDS dest = uniform base + lane*16
__device__ __forceinline__ void gll16(const void* g, void* l) {
    __builtin_amdgcn_global_load_lds(
        (const __attribute__((address_space(1))) unsigned int*)g,
        (__attribute__((address_space(3))) unsigned int*)l, 16, 0, 0);
}

// ================= fused preprocessing =================
__global__ __launch_bounds__(256) void prep_all(
    const float* __restrict__ Q, const float* __restrict__ keys,
    const float* __restrict__ lin_w,
    float* __restrict__ k2g, unsigned short* __restrict__ Kp,
    unsigned short* __restrict__ Qbp, unsigned short* __restrict__ Wp,
    float* __restrict__ cn, float* __restrict__ klout) {
    __shared__ unsigned short T2[32][66];
    const int bx = blockIdx.x;
    const int tid = threadIdx.x;
    if (bx < 1024) {
        int row = bx * 4 + (tid >> 6);
        int l = tid & 63;
        float4 v = *(const float4*)(keys + (size_t)row * Fc + l * 4);
        float s = v.x * v.x + v.y * v.y + v.z * v.z + v.w * v.w;
        s = waveReduceSum(s);
        if (l == 0) k2g[row] = s;
    } else if (bx < 1536) {
        int t = (bx - 1024) * 256 + tid;
        int lane = t & 63, ci = t >> 6;
        int ct = ci & 7, ks = (ci >> 3) & 7, wv = (ci >> 6) & 3, h = ci >> 8;
        int qd = lane >> 4, li = lane & 15;
        int col = h * 512 + wv * 128 + ct * 16 + li;
        const float* src = keys + (size_t)col * Fc + ks * 32 + qd * 8;
        float4 a = *(const float4*)src;
        float4 b = *(const float4*)(src + 4);
        *(ushort4*)(Kp + (size_t)t * 8) = make_ushort4(f2bf(a.x), f2bf(a.y), f2bf(a.z), f2bf(a.w));
        *(ushort4*)(Kp + (size_t)t * 8 + 4) = make_ushort4(f2bf(b.x), f2bf(b.y), f2bf(b.z), f2bf(b.w));
    } else if (bx < 3584) {
        int i = bx - 1536;
        int n0 = (i & 31) * 32, f0 = ((i >> 5) & 3) * 64, bb = i >> 7;
        {
            int n_l = tid >> 3, f_l = (tid & 7) * 8;
            const float* src = Q + ((size_t)(bb * Nc + n0 + n_l)) * Fc + f0 + f_l;
            float4 a = *(const float4*)src;
            float4 b = *(const float4*)(src + 4);
            T2[n_l][f_l + 0] = f2bf(a.x); T2[n_l][f_l + 1] = f2bf(a.y);
            T2[n_l][f_l + 2] = f2bf(a.z); T2[n_l][f_l + 3] = f2bf(a.w);
            T2[n_l][f_l + 4] = f2bf(b.x); T2[n_l][f_l + 5] = f2bf(b.y);
            T2[n_l][f_l + 6] = f2bf(b.z); T2[n_l][f_l + 7] = f2bf(b.w);
        }
        __syncthreads();
        int c = tid >> 6, L = tid & 63;
        int qd = L >> 4, li = L & 15;
        unsigned short o[8];
#pragma unroll
        for (int j = 0; j < 8; j++) o[j] = T2[qd * 8 + j][c * 16 + li];
        size_t idx = ((((size_t)bb * 16 + (f0 >> 4) + c) * 32 + (n0 >> 5)) * 64 + L) * 8;
        *(ushort4*)(Qbp + idx) = make_ushort4(o[0], o[1], o[2], o[3]);
        *(ushort4*)(Qbp + idx + 4) = make_ushort4(o[4], o[5], o[6], o[7]);
    } else if (bx < 3616) {
        int t = (bx - 3584) * 256 + tid;
        int lane = t & 63, ci = t >> 6;
        int ot = ci >> 3, fs = ci & 7;
        int qd = lane >> 4, li = lane & 15;
        const float* src = lin_w + (size_t)(ot * 16 + li) * Fc + fs * 32 + qd * 8;
        float4 a = *(const float4*)src;
        float4 b = *(const float4*)(src + 4);
        *(ushort4*)(Wp + (size_t)t * 8) = make_ushort4(f2bf(a.x), f2bf(a.y), f2bf(a.z), f2bf(a.w));
        *(ushort4*)(Wp + (size_t)t * 8 + 4) = make_ushort4(f2bf(b.x), f2bf(b.y), f2bf(b.z), f2bf(b.w));
    } else {
        int i = (bx - 3616) * 256 + tid;
        float4 z = make_float4(0.f, 0.f, 0.f, 0.f);
        float4* d = (float4*)(cn + (size_t)i * 16);
        d[0] = z; d[1] = z; d[2] = z; d[3] = z;
        if (bx == 3616 && tid == 0) *klout = 0.f;
    }
}

// ====== distance-GEMM: 512 thr / 32 rows; LDS-staged B via global_load_lds ======
// Pipeline: half-ksteps hs=0..127 (16 chunks x 1KB each), 3 bufs, depth 2.
// launch_bounds(512,2): 256-VGPR cap -> NO SPILL (the R8 failure mode).
__global__ __launch_bounds__(512, 2) void cmfma_kernel(
    const float* __restrict__ Q, const unsigned short* __restrict__ Kp,
    const float* __restrict__ k2g, const float* __restrict__ conv_w,
    const int* __restrict__ mask, float* __restrict__ C,
    float* __restrict__ cn, unsigned short* __restrict__ Ctp) {
    __shared__ __align__(16) short stageSh[3 * 16 * 512];   // 48 KB; reused as Tb16 after K-loop
    __shared__ float q2s[32];
    __shared__ float msh[32];
    __shared__ float redb[2][4][2][16];     // per-head parity slot
    __shared__ float mslot[4][2][16];
    __shared__ float eslot[4][2][16];
    const int tid = threadIdx.x;
    const int wv = tid >> 6, L = tid & 63;
    const int qd = L >> 4, li = L & 15;
    const int s = wv & 1, cg = wv >> 1;     // row-half, column-quarter
    const int gr0 = blockIdx.x * 32;
    const int b = gr0 >> 10;

    // ---- A-frags inline from fp32 Q + q2 ----
    v8s A[8];
    {
        float q2part = 0.f;
        const float* qrow = Q + (size_t)(gr0 + s * 16 + li) * Fc + qd * 8;
#pragma unroll
        for (int ks = 0; ks < 8; ks++) {
            float4 a = *(const float4*)(qrow + ks * 32);
            float4 bq = *(const float4*)(qrow + ks * 32 + 4);
            v8s f;
            f[0] = (short)f2bf(a.x);  f[1] = (short)f2bf(a.y);
            f[2] = (short)f2bf(a.z);  f[3] = (short)f2bf(a.w);
            f[4] = (short)f2bf(bq.x); f[5] = (short)f2bf(bq.y);
            f[6] = (short)f2bf(bq.z); f[7] = (short)f2bf(bq.w);
            A[ks] = f;
            q2part += a.x * a.x + a.y * a.y + a.z * a.z + a.w * a.w +
                      bq.x * bq.x + bq.y * bq.y + bq.z * bq.z + bq.w * bq.w;
        }
        q2part += __shfl_xor(q2part, 16);
        q2part += __shfl_xor(q2part, 32);
        if (cg == 0 && qd == 0) q2s[s * 16 + li] = q2part;
    }
    if (tid < 32) msh[tid] = (float)mask[gr0 + tid];

    v4f D[8], S[8];
#pragma unroll
    for (int ct = 0; ct < 8; ct++) {
        D[ct] = (v4f){0.f, 0.f, 0.f, 0.f};
        S[ct] = (v4f){0.f, 0.f, 0.f, 0.f};
    }

// stage half-kstep hn: wave wv loads chunks j=2wv, 2wv+1 of 16
#define ISSUE(hn)                                                              \
    do {                                                                       \
        int hh_f = (hn) >> 4, kk_f = ((hn) >> 1) & 7, half_f = (hn)&1;         \
        int buf_f = (hn) % 3;                                                  \
        _Pragma("unroll") for (int m = 0; m < 2; m++) {                        \
            int j = wv * 2 + m;                                                \
            int cgj = j >> 2, ctj = j & 3;                                     \
            int gchunk = ((hh_f * 4 + cgj) << 6) + kk_f * 8 + half_f * 4 + ctj;\
            gll16(Kp + (size_t)gchunk * 512 + L * 8,                           \
                  &stageSh[buf_f * 8192 + j * 512]);                           \
        }                                                                      \
    } while (0)

    ISSUE(0);
    ISSUE(1);

    lds_barrier();   // q2s/msh visible

    float q2r[4], mrow[4];
#pragma unroll
    for (int r = 0; r < 4; r++) {
        q2r[r] = q2s[s * 16 + qd * 4 + r];
        mrow[r] = msh[s * 16 + qd * 4 + r];
    }

    for (int hs = 0; hs < 128; ++hs) {
        // wait for own staged batch of hs: outstanding <= 4 -> keep <=2
        if (hs < 126) __builtin_amdgcn_s_waitcnt(0x0F72);   // vmcnt(2)
        else          __builtin_amdgcn_s_waitcnt(0x0F70);   // vmcnt(0) at tail
        __builtin_amdgcn_s_barrier();                        // all 16 chunks of buf[hs%3] in LDS
        if (hs < 126) ISSUE(hs + 2);                         // buf free: consumed at hs-1

        const int kk = (hs >> 1) & 7, half = hs & 1;
        const short* bufp = &stageSh[(hs % 3) * 8192 + (cg * 4) * 512 + L * 8];
        v8s B0v = *(const v8s*)(bufp + 0);
        v8s B1v = *(const v8s*)(bufp + 512);
        v8s B2v = *(const v8s*)(bufp + 1024);
        v8s B3v = *(const v8s*)(bufp + 1536);
        D[half * 4 + 0] = __builtin_amdgcn_mfma_f32_16x16x32_bf16(A[kk], B0v, D[half * 4 + 0], 0, 0, 0);
        D[half * 4 + 1] = __builtin_amdgcn_mfma_f32_16x16x32_bf16(A[kk], B1v, D[half * 4 + 1], 0, 0, 0);
        D[half * 4 + 2] = __builtin_amdgcn_mfma_f32_16x16x32_bf16(A[kk], B2v, D[half * 4 + 2], 0, 0, 0);
        D[half * 4 + 3] = __builtin_amdgcn_mfma_f32_16x16x32_bf16(A[kk], B3v, D[half * 4 + 3], 0, 0, 0);

        if ((hs & 15) == 15) {
            const int h = hs >> 4;
            float rs[4] = {0.f, 0.f, 0.f, 0.f};
#pragma unroll
            for (int ct = 0; ct < 8; ct++) {
                float k2v = k2g[h * Kc + cg * 128 + ct * 16 + li];
#pragma unroll
                for (int r = 0; r < 4; r++) {
                    float d2 = fmaxf(q2r[r] + k2v - 2.f * D[ct][r], 0.f) * mrow[r];
                    float t = __builtin_amdgcn_rcpf(1.f + d2);
                    D[ct][r] = t;
                    rs[r] += t;
                }
            }
#pragma unroll
            for (int r = 0; r < 4; r++) {
                rs[r] += __shfl_xor(rs[r], 1, 16);
                rs[r] += __shfl_xor(rs[r], 2, 16);
                rs[r] += __shfl_xor(rs[r], 4, 16);
                rs[r] += __shfl_xor(rs[r], 8, 16);
            }
            if (li == 0) {
#pragma unroll
                for (int r = 0; r < 4; r++) redb[h & 1][cg][s][qd * 4 + r] = rs[r];
            }
            lds_barrier();
            float wh = conv_w[h];
            float sc[4];
#pragma unroll
            for (int r = 0; r < 4; r++) {
                int rw = qd * 4 + r;
                float tot = redb[h & 1][0][s][rw] + redb[h & 1][1][s][rw] +
                            redb[h & 1][2][s][rw] + redb[h & 1][3][s][rw];
                sc[r] = wh * __builtin_amdgcn_rcpf(tot);
            }
#pragma unroll
            for (int ct = 0; ct < 8; ct++)
#pragma unroll
                for (int r = 0; r < 4; r++) {
                    S[ct][r] += sc[r] * D[ct][r];
                    D[ct][r] = 0.f;
                }
        }
    }
#undef ISSUE

    // ---- softmax over 512 cols ----
    float mx[4] = {-1e30f, -1e30f, -1e30f, -1e30f};
#pragma unroll
    for (int ct = 0; ct < 8; ct++)
#pragma unroll
        for (int r = 0; r < 4; r++) mx[r] = fmaxf(mx[r], S[ct][r]);
#pragma unroll
    for (int r = 0; r < 4; r++) {
        mx[r] = fmaxf(mx[r], __shfl_xor(mx[r], 1, 16));
        mx[r] = fmaxf(mx[r], __shfl_xor(mx[r], 2, 16));
        mx[r] = fmaxf(mx[r], __shfl_xor(mx[r], 4, 16));
        mx[r] = fmaxf(mx[r], __shfl_xor(mx[r], 8, 16));
    }
    if (li == 0) {
#pragma unroll
        for (int r = 0; r < 4; r++) mslot[cg][s][qd * 4 + r] = mx[r];
    }
    lds_barrier();
#pragma unroll
    for (int r = 0; r < 4; r++) {
        int rw = qd * 4 + r;
        mx[r] = fmaxf(fmaxf(mslot[0][s][rw], mslot[1][s][rw]),
                      fmaxf(mslot[2][s][rw], mslot[3][s][rw]));
    }
    float es[4] = {0.f, 0.f, 0.f, 0.f};
#pragma unroll
    for (int ct = 0; ct < 8; ct++)
#pragma unroll
        for (int r = 0; r < 4; r++) {
            float e = __expf(S[ct][r] - mx[r]);
            S[ct][r] = e;
            es[r] += e;
        }
#pragma unroll
    for (int r = 0; r < 4; r++) {
        es[r] += __shfl_xor(es[r], 1, 16);
        es[r] += __shfl_xor(es[r], 2, 16);
        es[r] += __shfl_xor(es[r], 4, 16);
        es[r] += __shfl_xor(es[r], 8, 16);
    }
    if (li == 0) {
#pragma unroll
        for (int r = 0; r < 4; r++) eslot[cg][s][qd * 4 + r] = es[r];
    }
    lds_barrier();
    float inv[4];
#pragma unroll
    for (int r = 0; r < 4; r++) {
        int rw = qd * 4 + r;
        float tot = eslot[0][s][rw] + eslot[1][s][rw] +
                    eslot[2][s][rw] + eslot[3][s][rw];
        inv[r] = mrow[r] / tot;
    }
    // C stores + cn atomics
#pragma unroll
    for (int ct = 0; ct < 8; ct++) {
        int k = cg * 128 + ct * 16 + li;
        float colsum = 0.f;
#pragma unroll
        for (int r = 0; r < 4; r++) {
            float cv = S[ct][r] * inv[r];
            C[(size_t)(gr0 + s * 16 + qd * 4 + r) * Kc + k] = cv;
            colsum += cv;
        }
        colsum += __shfl_xor(colsum, 16);
        colsum += __shfl_xor(colsum, 32);
        if (qd == 0) atomicAdd(&cn[b * Kc + k], colsum);
    }

    // ---- Ctp pack: reuse staging LDS as Tb16[512][20], two 16-row passes ----
    __syncthreads();   // full drain: staging DMA all landed, safe to reuse
    short (*Tb16)[20] = (short (*)[20])stageSh;
    const int ns0 = (gr0 & 1023) >> 5;
#pragma unroll
    for (int p = 0; p < 2; p++) {
        if (s == p) {
#pragma unroll
            for (int ct = 0; ct < 8; ct++) {
                int k = cg * 128 + ct * 16 + li;
                short4 t4;
                t4.x = (short)f2bf(S[ct][0] * inv[0]);
                t4.y = (short)f2bf(S[ct][1] * inv[1]);
                t4.z = (short)f2bf(S[ct][2] * inv[2]);
                t4.w = (short)f2bf(S[ct][3] * inv[3]);
                *(short4*)&Tb16[k][qd * 4] = t4;
            }
        }
        lds_barrier();
        {
            int k = tid;   // 512 threads = 512 k rows
            int kt = k >> 4, klo = k & 15;
            size_t cbase = (((size_t)b * 32 + kt) * 32 + ns0) * 512;
#pragma unroll
            for (int q2i = 0; q2i < 2; q2i++) {
                short4 lo = *(short4*)&Tb16[k][q2i * 8];
                short4 hi = *(short4*)&Tb16[k][q2i * 8 + 4];
                short4* d = (short4*)(Ctp + cbase + (size_t)((p * 2 + q2i) * 16 + klo) * 8);
                d[0] = lo; d[1] = hi;
            }
        }
        lds_barrier();
    }
}

// ---- fused: [0,512) vmfma (V = C^T Q -> Vp bf16 packed); [512,1536) kl ----
__global__ __launch_bounds__(256) void klv_kernel(
    const unsigned short* __restrict__ Ctp, const unsigned short* __restrict__ Qbp,
    unsigned short* __restrict__ Vp, const float* __restrict__ C,
    const float* __restrict__ cn, float* __restrict__ klout) {
    __shared__ short Vt[64][76];
    __shared__ float red[4];
    int tid = threadIdx.x;
    int bx = blockIdx.x;
    if (bx < 512) {
        int w = tid >> 6, L = tid & 63;
        int qd = L >> 4, li = L & 15;
        int wr = w >> 1, wc = w & 1;
        int bb = bx >> 5;
        int rem = bx & 31;
        int ktb = rem >> 2, ftb = rem & 3;
        int KT0 = ktb * 4 + wr * 2;
        int FT0 = ftb * 4 + wc * 2;
        const unsigned short* pa0 = Ctp + (((size_t)bb * 32 + KT0) * 32) * 512 + L * 8;
        const unsigned short* pa1 = pa0 + (size_t)32 * 512;
        const unsigned short* pb0 = Qbp + (((size_t)bb * 16 + FT0) * 32) * 512 + L * 8;
        const unsigned short* pb1 = pb0 + (size_t)32 * 512;
        v4f acc[2][2];
#pragma unroll
        for (int a = 0; a < 2; a++)
#pragma unroll
            for (int c = 0; c < 2; c++) acc[a][c] = (v4f){0.f, 0.f, 0.f, 0.f};

        v8s A0 = *(const v8s*)pa0, A1 = *(const v8s*)pa1;
        v8s B0 = *(const v8s*)pb0, B1 = *(const v8s*)pb1;
        for (int ns = 0; ns < 32; ns++) {
            int nsn = (ns + 1) & 31;
            v8s A0n = *(const v8s*)(pa0 + nsn * 512);
            v8s A1n = *(const v8s*)(pa1 + nsn * 512);
            v8s B0n = *(const v8s*)(pb0 + nsn * 512);
            v8s B1n = *(const v8s*)(pb1 + nsn * 512);
            acc[0][0] = __builtin_amdgcn_mfma_f32_16x16x32_bf16(A0, B0, acc[0][0], 0, 0, 0);
            acc[0][1] = __builtin_amdgcn_mfma_f32_16x16x32_bf16(A0, B1, acc[0][1], 0, 0, 0);
            acc[1][0] = __builtin_amdgcn_mfma_f32_16x16x32_bf16(A1, B0, acc[1][0], 0, 0, 0);
            acc[1][1] = __builtin_amdgcn_mfma_f32_16x16x32_bf16(A1, B1, acc[1][1], 0, 0, 0);
            A0 = A0n; A1 = A1n; B0 = B0n; B1 = B1n;
        }
#pragma unroll
        for (int a = 0; a < 2; a++)
#pragma unroll
            for (int c = 0; c < 2; c++)
#pragma unroll
                for (int r = 0; r < 4; r++)
                    Vt[(wr * 2 + a) * 16 + qd * 4 + r][(wc * 2 + c) * 16 + li] =
                        (short)f2bf(acc[a][c][r]);
        __syncthreads();
        {
            int ci = tid >> 5, s5 = tid & 31;
            int mtl = ci >> 1, fsl = ci & 1;
            size_t mt_g = (size_t)bb * 32 + ktb * 4 + mtl;
            size_t fs_g = (size_t)ftb * 2 + fsl;
#pragma unroll
            for (int half = 0; half < 2; half++) {
                int L2 = s5 + half * 32;
                int qd2 = L2 >> 4, li2 = L2 & 15;
                short4 x0 = *(short4*)&Vt[mtl * 16 + li2][fsl * 32 + qd2 * 8];
                short4 x1 = *(short4*)&Vt[mtl * 16 + li2][fsl * 32 + qd2 * 8 + 4];
                short4* d = (short4*)(Vp + ((mt_g * 8 + fs_g) * 64 + L2) * 8);
                d[0] = x0; d[1] = x1;
            }
        }
    } else {
        int bk = bx - 512;
        int w = tid >> 6, l = tid & 63;
        float kacc = 0.f;
#pragma unroll
        for (int rr = 0; rr < 4; rr++) {
            int row = bk * 16 + w * 4 + rr;
            int b = row >> 10;
            const float* cp = C + (size_t)row * Kc + l * 8;
            const float* np = cn + b * Kc + l * 8;
            float4 c0 = *(const float4*)cp;
            float4 c1 = *(const float4*)(cp + 4);
            float4 n0 = *(const float4*)np;
            float4 n1 = *(const float4*)(np + 4);
            float p[8];
            p[0] = c0.x * c0.x / (n0.x + EPSc); p[1] = c0.y * c0.y / (n0.y + EPSc);
            p[2] = c0.z * c0.z / (n0.z + EPSc); p[3] = c0.w * c0.w / (n0.w + EPSc);
            p[4] = c1.x * c1.x / (n1.x + EPSc); p[5] = c1.y * c1.y / (n1.y + EPSc);
            p[6] = c1.z * c1.z / (n1.z + EPSc); p[7] = c1.w * c1.w / (n1.w + EPSc);
            float s = p[0] + p[1] + p[2] + p[3] + p[4] + p[5] + p[6] + p[7];
            float pn = waveReduceSum(s) + EPSc;
            float rpn = 1.0f / pn;
            float cc[8] = {c0.x, c0.y, c0.z, c0.w, c1.x, c1.y, c1.z, c1.w};
#pragma unroll
            for (int j = 0; j < 8; j++) {
                float P = p[j] * rpn;
                kacc += P * __logf((P + EPSc) / (cc[j] + EPSc));
            }
        }
        kacc = waveReduceSum(kacc);
        if (l == 0) red[w] = kacc;
        __syncthreads();
        if (tid == 0)
            atomicAdd(klout, 100.f * (red[0] + red[1] + red[2] + red[3]));
    }
}

// ---- out = leaky_relu(Vp @ Wp^T + b) via MFMA ----
__global__ __launch_bounds__(256) void ofma_kernel(
    const unsigned short* __restrict__ Vp, const unsigned short* __restrict__ Wp,
    const float* __restrict__ bias, float* __restrict__ out) {
    int tid = threadIdx.x;
    int w = tid >> 6, L = tid & 63;
    int qd = L >> 4, li = L & 15;
    int wr = w >> 1, wc = w & 1;
    int MT0 = blockIdx.x * 4 + wr * 2;
    int OT0 = blockIdx.y * 4 + wc * 2;
    const unsigned short* pa0 = Vp + ((size_t)MT0 * 8) * 512 + L * 8;
    const unsigned short* pa1 = pa0 + (size_t)8 * 512;
    const unsigned short* pb0 = Wp + ((size_t)OT0 * 8) * 512 + L * 8;
    const unsigned short* pb1 = pb0 + (size_t)8 * 512;
    v4f acc[2][2];
#pragma unroll
    for (int a = 0; a < 2; a++)
#pragma unroll
        for (int c = 0; c < 2; c++) acc[a][c] = (v4f){0.f, 0.f, 0.f, 0.f};
#pragma unroll
    for (int fs = 0; fs < 8; fs++) {
        v8s A0 = *(const v8s*)(pa0 + fs * 512);
        v8s A1 = *(const v8s*)(pa1 + fs * 512);
        v8s B0 = *(const v8s*)(pb0 + fs * 512);
        v8s B1 = *(const v8s*)(pb1 + fs * 512);
        acc[0][0] = __builtin_amdgcn_mfma_f32_16x16x32_bf16(A0, B0, acc[0][0], 0, 0, 0);
        acc[0][1] = __builtin_amdgcn_mfma_f32_16x16x32_bf16(A0, B1, acc[0][1], 0, 0, 0);
        acc[1][0] = __builtin_amdgcn_mfma_f32_16x16x32_bf16(A1, B0, acc[1][0], 0, 0, 0);
        acc[1][1] = __builtin_amdgcn_mfma_f32_16x16x32_bf16(A1, B1, acc[1][1], 0, 0, 0);
    }
#pragma unroll
    for (int c = 0; c < 2; c++) {
        float bv = bias[(OT0 + c) * 16 + li];
#pragma unroll
        for (int a = 0; a < 2; a++)
#pragma unroll
            for (int r = 0; r < 4; r++) {
                int m = (MT0 + a) * 16 + qd * 4 + r;
                int o = (OT0 + c) * 16 + li;
                float x = acc[a][c][r] + bv;
                out[(size_t)m * DOUTc + o] = x > 0.f ? x : 0.01f * x;
            }
    }
}

extern "C" void kernel_launch(void* const* d_in, const int* in_sizes, int n_in,
                              void* d_out, int out_size, void* d_ws, size_t ws_size,
                              hipStream_t stream) {
    const float* Q = (const float*)d_in[0];
    const float* keys = (const float*)d_in[1];
    const float* conv_w = (const float*)d_in[2];
    const float* lin_w = (const float*)d_in[3];
    const float* lin_b = (const float*)d_in[4];
    const int* mask = (const int*)d_in[5];

    float* out = (float*)d_out;
    float* kl = out + (size_t)Bc * Kc * DOUTc;

    float* ws = (float*)d_ws;
    float* C = ws;                                   // 8,388,608 f
    float* k2 = C + (size_t)Bc * Nc * Kc;            // 4,096 f
    float* cn = k2 + (size_t)Hc * Kc;                // 8,192 f
    unsigned short* Kp = (unsigned short*)(cn + (size_t)Bc * Kc);  // 1,048,576 us
    unsigned short* Ctp = Kp + (size_t)Hc * Kc * Fc;               // 8,388,608 us
    unsigned short* Qbp = Ctp + (size_t)Bc * Nc * Kc;              // 4,194,304 us
    unsigned short* Vp = Qbp + (size_t)Bc * Nc * Fc;               // 2,097,152 us
    unsigned short* Wp = Vp + (size_t)Bc * Kc * Fc;                // 65,536 us

    prep_all<<<3618, 256, 0, stream>>>(Q, keys, lin_w, k2, Kp, Qbp, Wp, cn, kl);
    cmfma_kernel<<<Bc * Nc / 32, 512, 0, stream>>>(Q, Kp, k2, conv_w, mask, C, cn, Ctp);
    klv_kernel<<<1536, 256, 0, stream>>>(Ctp, Qbp, Vp, C, cn, kl);
    ofma_kernel<<<dim3(Bc * Kc / 64, DOUTc / 64), 256, 0, stream>>>(Vp, Wp, lin_b, out);
}

// Round 10
// 200.516 us; speedup vs baseline: 11.5065x; 11.5065x over previous
//
#include <hip/hip_runtime.h>
#include <math.h>

#define Bc 16
#define Nc 1024
#define Fc 256
#define Hc 8
#define Kc 512
#define DOUTc 256
#define EPSc 1e-8f

typedef short v8s __attribute__((ext_vector_type(8)));
typedef float v4f __attribute__((ext_vector_type(4)));

__device__ __forceinline__ float waveReduceSum(float v) {
    v += __shfl_xor(v, 32); v += __shfl_xor(v, 16); v += __shfl_xor(v, 8);
    v += __shfl_xor(v, 4);  v += __shfl_xor(v, 2);  v += __shfl_xor(v, 1);
    return v;
}

__device__ __forceinline__ unsigned short f2bf(float f) {
    unsigned int u = __float_as_uint(f);
    u = (u + 0x7fffu + ((u >> 16) & 1u)) >> 16;   // RNE
    return (unsigned short)u;
}

// ================= fused preprocessing =================
// [0,4096)    Q->Qb + q2       (4 rows/block)
// [4096,5120) k2               (4 key rows/block)
// [5120,5632) kpack -> Kp
// [5632,7680) qpack -> Qbp
// [7680,7712) wpack -> Wp
// [7712,7714) zero cn + kl
__global__ __launch_bounds__(256) void prep_all(
    const float* __restrict__ Q, const float* __restrict__ keys,
    const float* __restrict__ lin_w,
    unsigned short* __restrict__ Qb, float* __restrict__ q2g,
    float* __restrict__ k2g, unsigned short* __restrict__ Kp,
    unsigned short* __restrict__ Qbp, unsigned short* __restrict__ Wp,
    float* __restrict__ cn, float* __restrict__ klout) {
    __shared__ unsigned short T2[32][66];
    const int bx = blockIdx.x;
    const int tid = threadIdx.x;
    if (bx < 4096) {
        int row = bx * 4 + (tid >> 6);
        int l = tid & 63;
        float4 v = *(const float4*)(Q + (size_t)row * Fc + l * 4);
        float s = v.x * v.x + v.y * v.y + v.z * v.z + v.w * v.w;
        *(ushort4*)(Qb + (size_t)row * Fc + l * 4) =
            make_ushort4(f2bf(v.x), f2bf(v.y), f2bf(v.z), f2bf(v.w));
        s = waveReduceSum(s);
        if (l == 0) q2g[row] = s;
    } else if (bx < 5120) {
        int row = (bx - 4096) * 4 + (tid >> 6);
        int l = tid & 63;
        float4 v = *(const float4*)(keys + (size_t)row * Fc + l * 4);
        float s = v.x * v.x + v.y * v.y + v.z * v.z + v.w * v.w;
        s = waveReduceSum(s);
        if (l == 0) k2g[row] = s;
    } else if (bx < 5632) {
        int t = (bx - 5120) * 256 + tid;
        int lane = t & 63, ci = t >> 6;
        int ct = ci & 7, ks = (ci >> 3) & 7, wv = (ci >> 6) & 3, h = ci >> 8;
        int qd = lane >> 4, li = lane & 15;
        int col = h * 512 + wv * 128 + ct * 16 + li;
        const float* src = keys + (size_t)col * Fc + ks * 32 + qd * 8;
        float4 a = *(const float4*)src;
        float4 b = *(const float4*)(src + 4);
        *(ushort4*)(Kp + (size_t)t * 8) = make_ushort4(f2bf(a.x), f2bf(a.y), f2bf(a.z), f2bf(a.w));
        *(ushort4*)(Kp + (size_t)t * 8 + 4) = make_ushort4(f2bf(b.x), f2bf(b.y), f2bf(b.z), f2bf(b.w));
    } else if (bx < 7680) {
        int i = bx - 5632;
        int n0 = (i & 31) * 32, f0 = ((i >> 5) & 3) * 64, bb = i >> 7;
        {
            int n_l = tid >> 3, f_l = (tid & 7) * 8;
            const float* src = Q + ((size_t)(bb * Nc + n0 + n_l)) * Fc + f0 + f_l;
            float4 a = *(const float4*)src;
            float4 b = *(const float4*)(src + 4);
            T2[n_l][f_l + 0] = f2bf(a.x); T2[n_l][f_l + 1] = f2bf(a.y);
            T2[n_l][f_l + 2] = f2bf(a.z); T2[n_l][f_l + 3] = f2bf(a.w);
            T2[n_l][f_l + 4] = f2bf(b.x); T2[n_l][f_l + 5] = f2bf(b.y);
            T2[n_l][f_l + 6] = f2bf(b.z); T2[n_l][f_l + 7] = f2bf(b.w);
        }
        __syncthreads();
        int c = tid >> 6, L = tid & 63;
        int qd = L >> 4, li = L & 15;
        unsigned short o[8];
#pragma unroll
        for (int j = 0; j < 8; j++) o[j] = T2[qd * 8 + j][c * 16 + li];
        size_t idx = ((((size_t)bb * 16 + (f0 >> 4) + c) * 32 + (n0 >> 5)) * 64 + L) * 8;
        *(ushort4*)(Qbp + idx) = make_ushort4(o[0], o[1], o[2], o[3]);
        *(ushort4*)(Qbp + idx + 4) = make_ushort4(o[4], o[5], o[6], o[7]);
    } else if (bx < 7712) {
        int t = (bx - 7680) * 256 + tid;
        int lane = t & 63, ci = t >> 6;
        int ot = ci >> 3, fs = ci & 7;
        int qd = lane >> 4, li = lane & 15;
        const float* src = lin_w + (size_t)(ot * 16 + li) * Fc + fs * 32 + qd * 8;
        float4 a = *(const float4*)src;
        float4 b = *(const float4*)(src + 4);
        *(ushort4*)(Wp + (size_t)t * 8) = make_ushort4(f2bf(a.x), f2bf(a.y), f2bf(a.z), f2bf(a.w));
        *(ushort4*)(Wp + (size_t)t * 8 + 4) = make_ushort4(f2bf(b.x), f2bf(b.y), f2bf(b.z), f2bf(b.w));
    } else {
        int i = (bx - 7712) * 256 + tid;
        float4 z = make_float4(0.f, 0.f, 0.f, 0.f);
        float4* d = (float4*)(cn + (size_t)i * 16);
        d[0] = z; d[1] = z; d[2] = z; d[3] = z;
        if (bx == 7712 && tid == 0) *klout = 0.f;
    }
}

// ====== R5's cmfma (best measured: 91.4 us): 32 rows/block, 256 thr ======
__global__ __launch_bounds__(256, 1) void cmfma_kernel(
    const unsigned short* __restrict__ Qb, const unsigned short* __restrict__ Kp,
    const float* __restrict__ q2g, const float* __restrict__ k2g,
    const float* __restrict__ conv_w, const int* __restrict__ mask,
    float* __restrict__ C, float* __restrict__ cn,
    unsigned short* __restrict__ Ctp) {
    __shared__ float redbuf[4][32];
    __shared__ short Tb[512][36];
    const int tid = threadIdx.x;
    const int wv = tid >> 6, L = tid & 63;
    const int qd = L >> 4, li = L & 15;
    const int gr0 = blockIdx.x * 32;
    const int b = gr0 >> 10;

    float q2r[2][4], mrow[2][4];
#pragma unroll
    for (int s = 0; s < 2; s++)
#pragma unroll
        for (int r = 0; r < 4; r++) {
            int gr = gr0 + s * 16 + qd * 4 + r;
            q2r[s][r] = q2g[gr];
            mrow[s][r] = (float)mask[gr];
        }

    v8s A[2][8];
#pragma unroll
    for (int s = 0; s < 2; s++) {
        const unsigned short* qa = Qb + (size_t)(gr0 + s * 16 + li) * Fc + qd * 8;
#pragma unroll
        for (int ks = 0; ks < 8; ks++) A[s][ks] = *(const v8s*)(qa + ks * 32);
    }

    v4f D[2][8], S[2][8];
#pragma unroll
    for (int s = 0; s < 2; s++)
#pragma unroll
        for (int ct = 0; ct < 8; ct++) {
            D[s][ct] = (v4f){0.f, 0.f, 0.f, 0.f};
            S[s][ct] = (v4f){0.f, 0.f, 0.f, 0.f};
        }

    const unsigned short* kwbase = Kp + (size_t)L * 8;
    v8s Bc0[8], Bn[8];
    {
        const unsigned short* p0 = kwbase + (size_t)(wv * 64) * 512;
#pragma unroll
        for (int ct = 0; ct < 8; ct++) Bc0[ct] = *(const v8s*)(p0 + ct * 512);
    }

#define KSTEP(kk, CUR, NXT)                                                        \
    do {                                                                           \
        int hn = h * 8 + (kk) + 1;                                                 \
        int hh = (hn >> 3) & 7, kn = hn & 7;                                       \
        const unsigned short* pb =                                                 \
            kwbase + (size_t)(((hh * 4 + wv) * 64 + kn * 8)) * 512;                \
        _Pragma("unroll") for (int ct = 0; ct < 8; ct++)                           \
            NXT[ct] = *(const v8s*)(pb + ct * 512);                                \
        _Pragma("unroll") for (int ct = 0; ct < 8; ct++)                           \
            D[0][ct] = __builtin_amdgcn_mfma_f32_16x16x32_bf16(A[0][kk], CUR[ct],  \
                                                               D[0][ct], 0, 0, 0);\
        _Pragma("unroll") for (int ct = 0; ct < 8; ct++)                           \
            D[1][ct] = __builtin_amdgcn_mfma_f32_16x16x32_bf16(A[1][kk], CUR[ct],  \
                                                               D[1][ct], 0, 0, 0);\
    } while (0)

    for (int h = 0; h < Hc; ++h) {
        float wh = conv_w[h];
        KSTEP(0, Bc0, Bn); KSTEP(1, Bn, Bc0);
        KSTEP(2, Bc0, Bn); KSTEP(3, Bn, Bc0);
        KSTEP(4, Bc0, Bn); KSTEP(5, Bn, Bc0);
        KSTEP(6, Bc0, Bn); KSTEP(7, Bn, Bc0);

        float rs[2][4] = {{0.f, 0.f, 0.f, 0.f}, {0.f, 0.f, 0.f, 0.f}};
#pragma unroll
        for (int ct = 0; ct < 8; ct++) {
            float k2v = k2g[h * Kc + wv * 128 + ct * 16 + li];
#pragma unroll
            for (int s = 0; s < 2; s++)
#pragma unroll
                for (int r = 0; r < 4; r++) {
                    float d2 = fmaxf(q2r[s][r] + k2v - 2.f * D[s][ct][r], 0.f) * mrow[s][r];
                    float t = __builtin_amdgcn_rcpf(1.f + d2);
                    D[s][ct][r] = t;
                    rs[s][r] += t;
                }
        }
#pragma unroll
        for (int s = 0; s < 2; s++)
#pragma unroll
            for (int r = 0; r < 4; r++) {
                rs[s][r] += __shfl_xor(rs[s][r], 1, 16);
                rs[s][r] += __shfl_xor(rs[s][r], 2, 16);
                rs[s][r] += __shfl_xor(rs[s][r], 4, 16);
                rs[s][r] += __shfl_xor(rs[s][r], 8, 16);
            }
        if (li == 0) {
#pragma unroll
            for (int s = 0; s < 2; s++)
#pragma unroll
                for (int r = 0; r < 4; r++) redbuf[wv][s * 16 + qd * 4 + r] = rs[s][r];
        }
        __syncthreads();
        float sc[2][4];
#pragma unroll
        for (int s = 0; s < 2; s++)
#pragma unroll
            for (int r = 0; r < 4; r++) {
                int rw = s * 16 + qd * 4 + r;
                float tot = redbuf[0][rw] + redbuf[1][rw] + redbuf[2][rw] + redbuf[3][rw];
                sc[s][r] = wh * __builtin_amdgcn_rcpf(tot);
            }
        __syncthreads();
#pragma unroll
        for (int s = 0; s < 2; s++)
#pragma unroll
            for (int ct = 0; ct < 8; ct++)
#pragma unroll
                for (int r = 0; r < 4; r++) {
                    S[s][ct][r] += sc[s][r] * D[s][ct][r];
                    D[s][ct][r] = 0.f;
                }
    }
#undef KSTEP

    // softmax over 512 columns
    float mx[2][4] = {{-1e30f, -1e30f, -1e30f, -1e30f}, {-1e30f, -1e30f, -1e30f, -1e30f}};
#pragma unroll
    for (int s = 0; s < 2; s++)
#pragma unroll
        for (int ct = 0; ct < 8; ct++)
#pragma unroll
            for (int r = 0; r < 4; r++) mx[s][r] = fmaxf(mx[s][r], S[s][ct][r]);
#pragma unroll
    for (int s = 0; s < 2; s++)
#pragma unroll
        for (int r = 0; r < 4; r++) {
            mx[s][r] = fmaxf(mx[s][r], __shfl_xor(mx[s][r], 1, 16));
            mx[s][r] = fmaxf(mx[s][r], __shfl_xor(mx[s][r], 2, 16));
            mx[s][r] = fmaxf(mx[s][r], __shfl_xor(mx[s][r], 4, 16));
            mx[s][r] = fmaxf(mx[s][r], __shfl_xor(mx[s][r], 8, 16));
        }
    if (li == 0) {
#pragma unroll
        for (int s = 0; s < 2; s++)
#pragma unroll
            for (int r = 0; r < 4; r++) redbuf[wv][s * 16 + qd * 4 + r] = mx[s][r];
    }
    __syncthreads();
#pragma unroll
    for (int s = 0; s < 2; s++)
#pragma unroll
        for (int r = 0; r < 4; r++) {
            int rw = s * 16 + qd * 4 + r;
            mx[s][r] = fmaxf(fmaxf(redbuf[0][rw], redbuf[1][rw]),
                             fmaxf(redbuf[2][rw], redbuf[3][rw]));
        }
    __syncthreads();
    float es[2][4] = {{0.f, 0.f, 0.f, 0.f}, {0.f, 0.f, 0.f, 0.f}};
#pragma unroll
    for (int s = 0; s < 2; s++)
#pragma unroll
        for (int ct = 0; ct < 8; ct++)
#pragma unroll
            for (int r = 0; r < 4; r++) {
                float e = __expf(S[s][ct][r] - mx[s][r]);
                S[s][ct][r] = e;
                es[s][r] += e;
            }
#pragma unroll
    for (int s = 0; s < 2; s++)
#pragma unroll
        for (int r = 0; r < 4; r++) {
            es[s][r] += __shfl_xor(es[s][r], 1, 16);
            es[s][r] += __shfl_xor(es[s][r], 2, 16);
            es[s][r] += __shfl_xor(es[s][r], 4, 16);
            es[s][r] += __shfl_xor(es[s][r], 8, 16);
        }
    if (li == 0) {
#pragma unroll
        for (int s = 0; s < 2; s++)
#pragma unroll
            for (int r = 0; r < 4; r++) redbuf[wv][s * 16 + qd * 4 + r] = es[s][r];
    }
    __syncthreads();
    float inv[2][4];
#pragma unroll
    for (int s = 0; s < 2; s++)
#pragma unroll
        for (int r = 0; r < 4; r++) {
            int rw = s * 16 + qd * 4 + r;
            float tot = redbuf[0][rw] + redbuf[1][rw] + redbuf[2][rw] + redbuf[3][rw];
            inv[s][r] = mrow[s][r] / tot;
        }
#pragma unroll
    for (int ct = 0; ct < 8; ct++) {
        int k = wv * 128 + ct * 16 + li;
        float colsum = 0.f;
#pragma unroll
        for (int s = 0; s < 2; s++) {
            float cv[4];
#pragma unroll
            for (int r = 0; r < 4; r++) {
                cv[r] = S[s][ct][r] * inv[s][r];
                C[(size_t)(gr0 + s * 16 + qd * 4 + r) * Kc + k] = cv[r];
                colsum += cv[r];
            }
            short4 t4;
            t4.x = (short)f2bf(cv[0]); t4.y = (short)f2bf(cv[1]);
            t4.z = (short)f2bf(cv[2]); t4.w = (short)f2bf(cv[3]);
            *(short4*)&Tb[k][s * 16 + qd * 4] = t4;
        }
        colsum += __shfl_xor(colsum, 16);
        colsum += __shfl_xor(colsum, 32);
        if (qd == 0) atomicAdd(&cn[b * Kc + k], colsum);
    }
    __syncthreads();
    {
        const int ns0 = (gr0 & 1023) >> 5;
#pragma unroll
        for (int kk = 0; kk < 2; kk++) {
            int k = tid * 2 + kk;
            int kt = k >> 4, klo = k & 15;
            size_t cbase = (((size_t)b * 32 + kt) * 32 + ns0) * 512;
#pragma unroll
            for (int q2i = 0; q2i < 4; q2i++) {
                short4 lo = *(short4*)&Tb[k][q2i * 8];
                short4 hi = *(short4*)&Tb[k][q2i * 8 + 4];
                short4* d = (short4*)(Ctp + cbase + (size_t)(q2i * 16 + klo) * 8);
                d[0] = lo; d[1] = hi;
            }
        }
    }
}

// ---- vmfma: V = C^T Q -> Vp (bf16 packed), 512 blocks ----
__global__ __launch_bounds__(256) void vmfma_kernel(
    const unsigned short* __restrict__ Ctp, const unsigned short* __restrict__ Qbp,
    unsigned short* __restrict__ Vp) {
    __shared__ short Vt[64][76];
    int tid = threadIdx.x;
    int bx = blockIdx.x;
    int w = tid >> 6, L = tid & 63;
    int qd = L >> 4, li = L & 15;
    int wr = w >> 1, wc = w & 1;
    int bb = bx >> 5;
    int rem = bx & 31;
    int ktb = rem >> 2, ftb = rem & 3;
    int KT0 = ktb * 4 + wr * 2;
    int FT0 = ftb * 4 + wc * 2;
    const unsigned short* pa0 = Ctp + (((size_t)bb * 32 + KT0) * 32) * 512 + L * 8;
    const unsigned short* pa1 = pa0 + (size_t)32 * 512;
    const unsigned short* pb0 = Qbp + (((size_t)bb * 16 + FT0) * 32) * 512 + L * 8;
    const unsigned short* pb1 = pb0 + (size_t)32 * 512;
    v4f acc[2][2];
#pragma unroll
    for (int a = 0; a < 2; a++)
#pragma unroll
        for (int c = 0; c < 2; c++) acc[a][c] = (v4f){0.f, 0.f, 0.f, 0.f};

    v8s A0 = *(const v8s*)pa0, A1 = *(const v8s*)pa1;
    v8s B0 = *(const v8s*)pb0, B1 = *(const v8s*)pb1;
    for (int ns = 0; ns < 32; ns++) {
        int nsn = (ns + 1) & 31;
        v8s A0n = *(const v8s*)(pa0 + nsn * 512);
        v8s A1n = *(const v8s*)(pa1 + nsn * 512);
        v8s B0n = *(const v8s*)(pb0 + nsn * 512);
        v8s B1n = *(const v8s*)(pb1 + nsn * 512);
        acc[0][0] = __builtin_amdgcn_mfma_f32_16x16x32_bf16(A0, B0, acc[0][0], 0, 0, 0);
        acc[0][1] = __builtin_amdgcn_mfma_f32_16x16x32_bf16(A0, B1, acc[0][1], 0, 0, 0);
        acc[1][0] = __builtin_amdgcn_mfma_f32_16x16x32_bf16(A1, B0, acc[1][0], 0, 0, 0);
        acc[1][1] = __builtin_amdgcn_mfma_f32_16x16x32_bf16(A1, B1, acc[1][1], 0, 0, 0);
        A0 = A0n; A1 = A1n; B0 = B0n; B1 = B1n;
    }
#pragma unroll
    for (int a = 0; a < 2; a++)
#pragma unroll
        for (int c = 0; c < 2; c++)
#pragma unroll
            for (int r = 0; r < 4; r++)
                Vt[(wr * 2 + a) * 16 + qd * 4 + r][(wc * 2 + c) * 16 + li] =
                    (short)f2bf(acc[a][c][r]);
    __syncthreads();
    {
        int ci = tid >> 5, s5 = tid & 31;
        int mtl = ci >> 1, fsl = ci & 1;
        size_t mt_g = (size_t)bb * 32 + ktb * 4 + mtl;
        size_t fs_g = (size_t)ftb * 2 + fsl;
#pragma unroll
        for (int half = 0; half < 2; half++) {
            int L2 = s5 + half * 32;
            int qd2 = L2 >> 4, li2 = L2 & 15;
            short4 x0 = *(short4*)&Vt[mtl * 16 + li2][fsl * 32 + qd2 * 8];
            short4 x1 = *(short4*)&Vt[mtl * 16 + li2][fsl * 32 + qd2 * 8 + 4];
            short4* d = (short4*)(Vp + ((mt_g * 8 + fs_g) * 64 + L2) * 8);
            d[0] = x0; d[1] = x1;
        }
    }
}

// ---- fused tail: [0,512) out = leaky_relu(Vp@Wp^T + b); [512,1536) kl ----
__global__ __launch_bounds__(256) void ofma_kl_kernel(
    const unsigned short* __restrict__ Vp, const unsigned short* __restrict__ Wp,
    const float* __restrict__ bias, float* __restrict__ out,
    const float* __restrict__ C, const float* __restrict__ cn,
    float* __restrict__ klout) {
    __shared__ float red[4];
    int tid = threadIdx.x;
    int bx = blockIdx.x;
    if (bx < 512) {
        int w = tid >> 6, L = tid & 63;
        int qd = L >> 4, li = L & 15;
        int wr = w >> 1, wc = w & 1;
        int mtb = bx & 127, otb = bx >> 7;
        int MT0 = mtb * 4 + wr * 2;
        int OT0 = otb * 4 + wc * 2;
        const unsigned short* pa0 = Vp + ((size_t)MT0 * 8) * 512 + L * 8;
        const unsigned short* pa1 = pa0 + (size_t)8 * 512;
        const unsigned short* pb0 = Wp + ((size_t)OT0 * 8) * 512 + L * 8;
        const unsigned short* pb1 = pb0 + (size_t)8 * 512;
        v4f acc[2][2];
#pragma unroll
        for (int a = 0; a < 2; a++)
#pragma unroll
            for (int c = 0; c < 2; c++) acc[a][c] = (v4f){0.f, 0.f, 0.f, 0.f};
#pragma unroll
        for (int fs = 0; fs < 8; fs++) {
            v8s A0 = *(const v8s*)(pa0 + fs * 512);
            v8s A1 = *(const v8s*)(pa1 + fs * 512);
            v8s B0 = *(const v8s*)(pb0 + fs * 512);
            v8s B1 = *(const v8s*)(pb1 + fs * 512);
            acc[0][0] = __builtin_amdgcn_mfma_f32_16x16x32_bf16(A0, B0, acc[0][0], 0, 0, 0);
            acc[0][1] = __builtin_amdgcn_mfma_f32_16x16x32_bf16(A0, B1, acc[0][1], 0, 0, 0);
            acc[1][0] = __builtin_amdgcn_mfma_f32_16x16x32_bf16(A1, B0, acc[1][0], 0, 0, 0);
            acc[1][1] = __builtin_amdgcn_mfma_f32_16x16x32_bf16(A1, B1, acc[1][1], 0, 0, 0);
        }
#pragma unroll
        for (int c = 0; c < 2; c++) {
            float bv = bias[(OT0 + c) * 16 + li];
#pragma unroll
            for (int a = 0; a < 2; a++)
#pragma unroll
                for (int r = 0; r < 4; r++) {
                    int m = (MT0 + a) * 16 + qd * 4 + r;
                    int o = (OT0 + c) * 16 + li;
                    float x = acc[a][c][r] + bv;
                    out[(size_t)m * DOUTc + o] = x > 0.f ? x : 0.01f * x;
                }
        }
    } else {
        int bk = bx - 512;
        int w = tid >> 6, l = tid & 63;
        float kacc = 0.f;
#pragma unroll
        for (int rr = 0; rr < 4; rr++) {
            int row = bk * 16 + w * 4 + rr;
            int b = row >> 10;
            const float* cp = C + (size_t)row * Kc + l * 8;
            const float* np = cn + b * Kc + l * 8;
            float4 c0 = *(const float4*)cp;
            float4 c1 = *(const float4*)(cp + 4);
            float4 n0 = *(const float4*)np;
            float4 n1 = *(const float4*)(np + 4);
            float p[8];
            p[0] = c0.x * c0.x / (n0.x + EPSc); p[1] = c0.y * c0.y / (n0.y + EPSc);
            p[2] = c0.z * c0.z / (n0.z + EPSc); p[3] = c0.w * c0.w / (n0.w + EPSc);
            p[4] = c1.x * c1.x / (n1.x + EPSc); p[5] = c1.y * c1.y / (n1.y + EPSc);
            p[6] = c1.z * c1.z / (n1.z + EPSc); p[7] = c1.w * c1.w / (n1.w + EPSc);
            float s = p[0] + p[1] + p[2] + p[3] + p[4] + p[5] + p[6] + p[7];
            float pn = waveReduceSum(s) + EPSc;
            float rpn = 1.0f / pn;
            float cc[8] = {c0.x, c0.y, c0.z, c0.w, c1.x, c1.y, c1.z, c1.w};
#pragma unroll
            for (int j = 0; j < 8; j++) {
                float P = p[j] * rpn;
                kacc += P * __logf((P + EPSc) / (cc[j] + EPSc));
            }
        }
        kacc = waveReduceSum(kacc);
        if (l == 0) red[w] = kacc;
        __syncthreads();
        if (tid == 0)
            atomicAdd(klout, 100.f * (red[0] + red[1] + red[2] + red[3]));
    }
}

extern "C" void kernel_launch(void* const* d_in, const int* in_sizes, int n_in,
                              void* d_out, int out_size, void* d_ws, size_t ws_size,
                              hipStream_t stream) {
    const float* Q = (const float*)d_in[0];
    const float* keys = (const float*)d_in[1];
    const float* conv_w = (const float*)d_in[2];
    const float* lin_w = (const float*)d_in[3];
    const float* lin_b = (const float*)d_in[4];
    const int* mask = (const int*)d_in[5];

    float* out = (float*)d_out;
    float* kl = out + (size_t)Bc * Kc * DOUTc;

    float* ws = (float*)d_ws;
    float* C = ws;                                   // 8,388,608 f
    float* k2 = C + (size_t)Bc * Nc * Kc;            // 4,096 f
    float* cn = k2 + (size_t)Hc * Kc;                // 8,192 f
    float* q2 = cn + (size_t)Bc * Kc;                // 16,384 f
    unsigned short* Qb = (unsigned short*)(q2 + (size_t)Bc * Nc);  // 4,194,304 us
    unsigned short* Kp = Qb + (size_t)Bc * Nc * Fc;                // 1,048,576 us
    unsigned short* Ctp = Kp + (size_t)Hc * Kc * Fc;               // 8,388,608 us
    unsigned short* Qbp = Ctp + (size_t)Bc * Nc * Kc;              // 4,194,304 us
    unsigned short* Vp = Qbp + (size_t)Bc * Nc * Fc;               // 2,097,152 us
    unsigned short* Wp = Vp + (size_t)Bc * Kc * Fc;                // 65,536 us

    prep_all<<<7714, 256, 0, stream>>>(Q, keys, lin_w, Qb, q2, k2, Kp, Qbp, Wp, cn, kl);
    cmfma_kernel<<<Bc * Nc / 32, 256, 0, stream>>>(Qb, Kp, q2, k2, conv_w, mask, C, cn, Ctp);
    vmfma_kernel<<<512, 256, 0, stream>>>(Ctp, Qbp, Vp);
    ofma_kl_kernel<<<1536, 256, 0, stream>>>(Vp, Wp, lin_b, out, C, cn, kl);
}

// Round 11
// 192.926 us; speedup vs baseline: 11.9592x; 1.0393x over previous
//
#include <hip/hip_runtime.h>
#include <math.h>

#define Bc 16
#define Nc 1024
#define Fc 256
#define Hc 8
#define Kc 512
#define DOUTc 256
#define EPSc 1e-8f

typedef short v8s __attribute__((ext_vector_type(8)));
typedef float v4f __attribute__((ext_vector_type(4)));

__device__ __forceinline__ float waveReduceSum(float v) {
    v += __shfl_xor(v, 32); v += __shfl_xor(v, 16); v += __shfl_xor(v, 8);
    v += __shfl_xor(v, 4);  v += __shfl_xor(v, 2);  v += __shfl_xor(v, 1);
    return v;
}

__device__ __forceinline__ unsigned short f2bf(float f) {
    unsigned int u = __float_as_uint(f);
    u = (u + 0x7fffu + ((u >> 16) & 1u)) >> 16;   // RNE
    return (unsigned short)u;
}

// ================= fused preprocessing =================
// [0,4096)    Q->Qb + q2       (4 rows/block)
// [4096,5120) k2               (4 key rows/block)
// [5120,5632) kpack -> Kp
// [5632,7680) qpack -> Qbp
// [7680,7712) wpack -> Wp
// [7712,7714) zero cn + kl
__global__ __launch_bounds__(256) void prep_all(
    const float* __restrict__ Q, const float* __restrict__ keys,
    const float* __restrict__ lin_w,
    unsigned short* __restrict__ Qb, float* __restrict__ q2g,
    float* __restrict__ k2g, unsigned short* __restrict__ Kp,
    unsigned short* __restrict__ Qbp, unsigned short* __restrict__ Wp,
    float* __restrict__ cn, float* __restrict__ klout) {
    __shared__ unsigned short T2[32][66];
    const int bx = blockIdx.x;
    const int tid = threadIdx.x;
    if (bx < 4096) {
        int row = bx * 4 + (tid >> 6);
        int l = tid & 63;
        float4 v = *(const float4*)(Q + (size_t)row * Fc + l * 4);
        float s = v.x * v.x + v.y * v.y + v.z * v.z + v.w * v.w;
        *(ushort4*)(Qb + (size_t)row * Fc + l * 4) =
            make_ushort4(f2bf(v.x), f2bf(v.y), f2bf(v.z), f2bf(v.w));
        s = waveReduceSum(s);
        if (l == 0) q2g[row] = s;
    } else if (bx < 5120) {
        int row = (bx - 4096) * 4 + (tid >> 6);
        int l = tid & 63;
        float4 v = *(const float4*)(keys + (size_t)row * Fc + l * 4);
        float s = v.x * v.x + v.y * v.y + v.z * v.z + v.w * v.w;
        s = waveReduceSum(s);
        if (l == 0) k2g[row] = s;
    } else if (bx < 5632) {
        int t = (bx - 5120) * 256 + tid;
        int lane = t & 63, ci = t >> 6;
        int ct = ci & 7, ks = (ci >> 3) & 7, wv = (ci >> 6) & 3, h = ci >> 8;
        int qd = lane >> 4, li = lane & 15;
        int col = h * 512 + wv * 128 + ct * 16 + li;
        const float* src = keys + (size_t)col * Fc + ks * 32 + qd * 8;
        float4 a = *(const float4*)src;
        float4 b = *(const float4*)(src + 4);
        *(ushort4*)(Kp + (size_t)t * 8) = make_ushort4(f2bf(a.x), f2bf(a.y), f2bf(a.z), f2bf(a.w));
        *(ushort4*)(Kp + (size_t)t * 8 + 4) = make_ushort4(f2bf(b.x), f2bf(b.y), f2bf(b.z), f2bf(b.w));
    } else if (bx < 7680) {
        int i = bx - 5632;
        int n0 = (i & 31) * 32, f0 = ((i >> 5) & 3) * 64, bb = i >> 7;
        {
            int n_l = tid >> 3, f_l = (tid & 7) * 8;
            const float* src = Q + ((size_t)(bb * Nc + n0 + n_l)) * Fc + f0 + f_l;
            float4 a = *(const float4*)src;
            float4 b = *(const float4*)(src + 4);
            T2[n_l][f_l + 0] = f2bf(a.x); T2[n_l][f_l + 1] = f2bf(a.y);
            T2[n_l][f_l + 2] = f2bf(a.z); T2[n_l][f_l + 3] = f2bf(a.w);
            T2[n_l][f_l + 4] = f2bf(b.x); T2[n_l][f_l + 5] = f2bf(b.y);
            T2[n_l][f_l + 6] = f2bf(b.z); T2[n_l][f_l + 7] = f2bf(b.w);
        }
        __syncthreads();
        int c = tid >> 6, L = tid & 63;
        int qd = L >> 4, li = L & 15;
        unsigned short o[8];
#pragma unroll
        for (int j = 0; j < 8; j++) o[j] = T2[qd * 8 + j][c * 16 + li];
        size_t idx = ((((size_t)bb * 16 + (f0 >> 4) + c) * 32 + (n0 >> 5)) * 64 + L) * 8;
        *(ushort4*)(Qbp + idx) = make_ushort4(o[0], o[1], o[2], o[3]);
        *(ushort4*)(Qbp + idx + 4) = make_ushort4(o[4], o[5], o[6], o[7]);
    } else if (bx < 7712) {
        int t = (bx - 7680) * 256 + tid;
        int lane = t & 63, ci = t >> 6;
        int ot = ci >> 3, fs = ci & 7;
        int qd = lane >> 4, li = lane & 15;
        const float* src = lin_w + (size_t)(ot * 16 + li) * Fc + fs * 32 + qd * 8;
        float4 a = *(const float4*)src;
        float4 b = *(const float4*)(src + 4);
        *(ushort4*)(Wp + (size_t)t * 8) = make_ushort4(f2bf(a.x), f2bf(a.y), f2bf(a.z), f2bf(a.w));
        *(ushort4*)(Wp + (size_t)t * 8 + 4) = make_ushort4(f2bf(b.x), f2bf(b.y), f2bf(b.z), f2bf(b.w));
    } else {
        int i = (bx - 7712) * 256 + tid;
        float4 z = make_float4(0.f, 0.f, 0.f, 0.f);
        float4* d = (float4*)(cn + (size_t)i * 16);
        d[0] = z; d[1] = z; d[2] = z; d[3] = z;
        if (bx == 7712 && tid == 0) *klout = 0.f;
    }
}

// ====== cmfma (best measured: 91.4 us): 32 rows/block, 256 thr ======
__global__ __launch_bounds__(256, 1) void cmfma_kernel(
    const unsigned short* __restrict__ Qb, const unsigned short* __restrict__ Kp,
    const float* __restrict__ q2g, const float* __restrict__ k2g,
    const float* __restrict__ conv_w, const int* __restrict__ mask,
    float* __restrict__ C, float* __restrict__ cn,
    unsigned short* __restrict__ Ctp) {
    __shared__ float redbuf[4][32];
    __shared__ short Tb[512][36];
    const int tid = threadIdx.x;
    const int wv = tid >> 6, L = tid & 63;
    const int qd = L >> 4, li = L & 15;
    const int gr0 = blockIdx.x * 32;
    const int b = gr0 >> 10;

    float q2r[2][4], mrow[2][4];
#pragma unroll
    for (int s = 0; s < 2; s++)
#pragma unroll
        for (int r = 0; r < 4; r++) {
            int gr = gr0 + s * 16 + qd * 4 + r;
            q2r[s][r] = q2g[gr];
            mrow[s][r] = (float)mask[gr];
        }

    v8s A[2][8];
#pragma unroll
    for (int s = 0; s < 2; s++) {
        const unsigned short* qa = Qb + (size_t)(gr0 + s * 16 + li) * Fc + qd * 8;
#pragma unroll
        for (int ks = 0; ks < 8; ks++) A[s][ks] = *(const v8s*)(qa + ks * 32);
    }

    v4f D[2][8], S[2][8];
#pragma unroll
    for (int s = 0; s < 2; s++)
#pragma unroll
        for (int ct = 0; ct < 8; ct++) {
            D[s][ct] = (v4f){0.f, 0.f, 0.f, 0.f};
            S[s][ct] = (v4f){0.f, 0.f, 0.f, 0.f};
        }

    const unsigned short* kwbase = Kp + (size_t)L * 8;
    v8s Bc0[8], Bn[8];
    {
        const unsigned short* p0 = kwbase + (size_t)(wv * 64) * 512;
#pragma unroll
        for (int ct = 0; ct < 8; ct++) Bc0[ct] = *(const v8s*)(p0 + ct * 512);
    }

#define KSTEP(kk, CUR, NXT)                                                        \
    do {                                                                           \
        int hn = h * 8 + (kk) + 1;                                                 \
        int hh = (hn >> 3) & 7, kn = hn & 7;                                       \
        const unsigned short* pb =                                                 \
            kwbase + (size_t)(((hh * 4 + wv) * 64 + kn * 8)) * 512;                \
        _Pragma("unroll") for (int ct = 0; ct < 8; ct++)                           \
            NXT[ct] = *(const v8s*)(pb + ct * 512);                                \
        _Pragma("unroll") for (int ct = 0; ct < 8; ct++)                           \
            D[0][ct] = __builtin_amdgcn_mfma_f32_16x16x32_bf16(A[0][kk], CUR[ct],  \
                                                               D[0][ct], 0, 0, 0);\
        _Pragma("unroll") for (int ct = 0; ct < 8; ct++)                           \
            D[1][ct] = __builtin_amdgcn_mfma_f32_16x16x32_bf16(A[1][kk], CUR[ct],  \
                                                               D[1][ct], 0, 0, 0);\
    } while (0)

    for (int h = 0; h < Hc; ++h) {
        float wh = conv_w[h];
        KSTEP(0, Bc0, Bn); KSTEP(1, Bn, Bc0);
        KSTEP(2, Bc0, Bn); KSTEP(3, Bn, Bc0);
        KSTEP(4, Bc0, Bn); KSTEP(5, Bn, Bc0);
        KSTEP(6, Bc0, Bn); KSTEP(7, Bn, Bc0);

        float rs[2][4] = {{0.f, 0.f, 0.f, 0.f}, {0.f, 0.f, 0.f, 0.f}};
#pragma unroll
        for (int ct = 0; ct < 8; ct++) {
            float k2v = k2g[h * Kc + wv * 128 + ct * 16 + li];
#pragma unroll
            for (int s = 0; s < 2; s++)
#pragma unroll
                for (int r = 0; r < 4; r++) {
                    float d2 = fmaxf(q2r[s][r] + k2v - 2.f * D[s][ct][r], 0.f) * mrow[s][r];
                    float t = __builtin_amdgcn_rcpf(1.f + d2);
                    D[s][ct][r] = t;
                    rs[s][r] += t;
                }
        }
#pragma unroll
        for (int s = 0; s < 2; s++)
#pragma unroll
            for (int r = 0; r < 4; r++) {
                rs[s][r] += __shfl_xor(rs[s][r], 1, 16);
                rs[s][r] += __shfl_xor(rs[s][r], 2, 16);
                rs[s][r] += __shfl_xor(rs[s][r], 4, 16);
                rs[s][r] += __shfl_xor(rs[s][r], 8, 16);
            }
        if (li == 0) {
#pragma unroll
            for (int s = 0; s < 2; s++)
#pragma unroll
                for (int r = 0; r < 4; r++) redbuf[wv][s * 16 + qd * 4 + r] = rs[s][r];
        }
        __syncthreads();
        float sc[2][4];
#pragma unroll
        for (int s = 0; s < 2; s++)
#pragma unroll
            for (int r = 0; r < 4; r++) {
                int rw = s * 16 + qd * 4 + r;
                float tot = redbuf[0][rw] + redbuf[1][rw] + redbuf[2][rw] + redbuf[3][rw];
                sc[s][r] = wh * __builtin_amdgcn_rcpf(tot);
            }
        __syncthreads();
#pragma unroll
        for (int s = 0; s < 2; s++)
#pragma unroll
            for (int ct = 0; ct < 8; ct++)
#pragma unroll
                for (int r = 0; r < 4; r++) {
                    S[s][ct][r] += sc[s][r] * D[s][ct][r];
                    D[s][ct][r] = 0.f;
                }
    }
#undef KSTEP

    // softmax over 512 columns
    float mx[2][4] = {{-1e30f, -1e30f, -1e30f, -1e30f}, {-1e30f, -1e30f, -1e30f, -1e30f}};
#pragma unroll
    for (int s = 0; s < 2; s++)
#pragma unroll
        for (int ct = 0; ct < 8; ct++)
#pragma unroll
            for (int r = 0; r < 4; r++) mx[s][r] = fmaxf(mx[s][r], S[s][ct][r]);
#pragma unroll
    for (int s = 0; s < 2; s++)
#pragma unroll
        for (int r = 0; r < 4; r++) {
            mx[s][r] = fmaxf(mx[s][r], __shfl_xor(mx[s][r], 1, 16));
            mx[s][r] = fmaxf(mx[s][r], __shfl_xor(mx[s][r], 2, 16));
            mx[s][r] = fmaxf(mx[s][r], __shfl_xor(mx[s][r], 4, 16));
            mx[s][r] = fmaxf(mx[s][r], __shfl_xor(mx[s][r], 8, 16));
        }
    if (li == 0) {
#pragma unroll
        for (int s = 0; s < 2; s++)
#pragma unroll
            for (int r = 0; r < 4; r++) redbuf[wv][s * 16 + qd * 4 + r] = mx[s][r];
    }
    __syncthreads();
#pragma unroll
    for (int s = 0; s < 2; s++)
#pragma unroll
        for (int r = 0; r < 4; r++) {
            int rw = s * 16 + qd * 4 + r;
            mx[s][r] = fmaxf(fmaxf(redbuf[0][rw], redbuf[1][rw]),
                             fmaxf(redbuf[2][rw], redbuf[3][rw]));
        }
    __syncthreads();
    float es[2][4] = {{0.f, 0.f, 0.f, 0.f}, {0.f, 0.f, 0.f, 0.f}};
#pragma unroll
    for (int s = 0; s < 2; s++)
#pragma unroll
        for (int ct = 0; ct < 8; ct++)
#pragma unroll
            for (int r = 0; r < 4; r++) {
                float e = __expf(S[s][ct][r] - mx[s][r]);
                S[s][ct][r] = e;
                es[s][r] += e;
            }
#pragma unroll
    for (int s = 0; s < 2; s++)
#pragma unroll
        for (int r = 0; r < 4; r++) {
            es[s][r] += __shfl_xor(es[s][r], 1, 16);
            es[s][r] += __shfl_xor(es[s][r], 2, 16);
            es[s][r] += __shfl_xor(es[s][r], 4, 16);
            es[s][r] += __shfl_xor(es[s][r], 8, 16);
        }
    if (li == 0) {
#pragma unroll
        for (int s = 0; s < 2; s++)
#pragma unroll
            for (int r = 0; r < 4; r++) redbuf[wv][s * 16 + qd * 4 + r] = es[s][r];
    }
    __syncthreads();
    float inv[2][4];
#pragma unroll
    for (int s = 0; s < 2; s++)
#pragma unroll
        for (int r = 0; r < 4; r++) {
            int rw = s * 16 + qd * 4 + r;
            float tot = redbuf[0][rw] + redbuf[1][rw] + redbuf[2][rw] + redbuf[3][rw];
            inv[s][r] = mrow[s][r] / tot;
        }
#pragma unroll
    for (int ct = 0; ct < 8; ct++) {
        int k = wv * 128 + ct * 16 + li;
        float colsum = 0.f;
#pragma unroll
        for (int s = 0; s < 2; s++) {
            float cv[4];
#pragma unroll
            for (int r = 0; r < 4; r++) {
                cv[r] = S[s][ct][r] * inv[s][r];
                C[(size_t)(gr0 + s * 16 + qd * 4 + r) * Kc + k] = cv[r];
                colsum += cv[r];
            }
            short4 t4;
            t4.x = (short)f2bf(cv[0]); t4.y = (short)f2bf(cv[1]);
            t4.z = (short)f2bf(cv[2]); t4.w = (short)f2bf(cv[3]);
            *(short4*)&Tb[k][s * 16 + qd * 4] = t4;
        }
        colsum += __shfl_xor(colsum, 16);
        colsum += __shfl_xor(colsum, 32);
        if (qd == 0) atomicAdd(&cn[b * Kc + k], colsum);
    }
    __syncthreads();
    {
        const int ns0 = (gr0 & 1023) >> 5;
#pragma unroll
        for (int kk = 0; kk < 2; kk++) {
            int k = tid * 2 + kk;
            int kt = k >> 4, klo = k & 15;
            size_t cbase = (((size_t)b * 32 + kt) * 32 + ns0) * 512;
#pragma unroll
            for (int q2i = 0; q2i < 4; q2i++) {
                short4 lo = *(short4*)&Tb[k][q2i * 8];
                short4 hi = *(short4*)&Tb[k][q2i * 8 + 4];
                short4* d = (short4*)(Ctp + cbase + (size_t)(q2i * 16 + klo) * 8);
                d[0] = lo; d[1] = hi;
            }
        }
    }
}

// ---- fused tail: [0,512) V=C^T Q (16k x 256f, regs) -> LDS -> out = leaky(V W^T + b)
//      [512,1536) kl ----
__global__ __launch_bounds__(256) void vout_kl_kernel(
    const unsigned short* __restrict__ Ctp, const unsigned short* __restrict__ Qbp,
    const unsigned short* __restrict__ Wp, const float* __restrict__ bias,
    float* __restrict__ out, const float* __restrict__ C,
    const float* __restrict__ cn, float* __restrict__ klout) {
    __shared__ short Vt[16][264];   // row stride 528 B: 16B-aligned, 2-way bank alias (free)
    __shared__ float red[4];
    int tid = threadIdx.x;
    int bx = blockIdx.x;
    if (bx < 512) {
        int w = tid >> 6, L = tid & 63;
        int qd = L >> 4, li = L & 15;
        int bb = bx >> 5, kt = bx & 31;
        // ---- phase A: V16 = C^T Q (k-tile kt, all 256 f) ----
        const unsigned short* pa = Ctp + (((size_t)bb * 32 + kt) * 32) * 512 + L * 8;
        const unsigned short* pbb = Qbp + (((size_t)bb * 16 + w * 4) * 32) * 512 + L * 8;
        v4f acc[4];
#pragma unroll
        for (int c = 0; c < 4; c++) acc[c] = (v4f){0.f, 0.f, 0.f, 0.f};
        v8s Ac = *(const v8s*)pa;
        v8s Bv[4];
#pragma unroll
        for (int c = 0; c < 4; c++) Bv[c] = *(const v8s*)(pbb + (size_t)(c * 32) * 512);
        for (int ns = 0; ns < 32; ns++) {
            int nsn = (ns + 1) & 31;
            v8s An = *(const v8s*)(pa + (size_t)nsn * 512);
            v8s Bn[4];
#pragma unroll
            for (int c = 0; c < 4; c++)
                Bn[c] = *(const v8s*)(pbb + (size_t)(c * 32 + nsn) * 512);
#pragma unroll
            for (int c = 0; c < 4; c++)
                acc[c] = __builtin_amdgcn_mfma_f32_16x16x32_bf16(Ac, Bv[c], acc[c], 0, 0, 0);
            Ac = An;
#pragma unroll
            for (int c = 0; c < 4; c++) Bv[c] = Bn[c];
        }
        // stage bf16 V-tile (16 k x 256 f) to LDS
#pragma unroll
        for (int c = 0; c < 4; c++)
#pragma unroll
            for (int r = 0; r < 4; r++)
                Vt[qd * 4 + r][(w * 4 + c) * 16 + li] = (short)f2bf(acc[c][r]);
        __syncthreads();
        // ---- phase B: out16 = leaky(V @ W^T + b); A from LDS, B = Wp (L2-hot) ----
        v4f o2[4];
#pragma unroll
        for (int c = 0; c < 4; c++) o2[c] = (v4f){0.f, 0.f, 0.f, 0.f};
        const unsigned short* pw = Wp + ((size_t)(w * 4) * 8) * 512 + L * 8;
#pragma unroll
        for (int fs = 0; fs < 8; fs++) {
            v8s Af = *(const v8s*)&Vt[li][fs * 32 + qd * 8];
#pragma unroll
            for (int c = 0; c < 4; c++) {
                v8s Bw = *(const v8s*)(pw + (size_t)(c * 8 + fs) * 512);
                o2[c] = __builtin_amdgcn_mfma_f32_16x16x32_bf16(Af, Bw, o2[c], 0, 0, 0);
            }
        }
#pragma unroll
        for (int c = 0; c < 4; c++) {
            float bv = bias[(w * 4 + c) * 16 + li];
#pragma unroll
            for (int r = 0; r < 4; r++) {
                float x = o2[c][r] + bv;
                out[((size_t)bb * 512 + kt * 16 + qd * 4 + r) * DOUTc + (w * 4 + c) * 16 + li] =
                    x > 0.f ? x : 0.01f * x;
            }
        }
    } else {
        int bk = bx - 512;
        int w = tid >> 6, l = tid & 63;
        float kacc = 0.f;
#pragma unroll
        for (int rr = 0; rr < 4; rr++) {
            int row = bk * 16 + w * 4 + rr;
            int b = row >> 10;
            const float* cp = C + (size_t)row * Kc + l * 8;
            const float* np = cn + b * Kc + l * 8;
            float4 c0 = *(const float4*)cp;
            float4 c1 = *(const float4*)(cp + 4);
            float4 n0 = *(const float4*)np;
            float4 n1 = *(const float4*)(np + 4);
            float p[8];
            p[0] = c0.x * c0.x / (n0.x + EPSc); p[1] = c0.y * c0.y / (n0.y + EPSc);
            p[2] = c0.z * c0.z / (n0.z + EPSc); p[3] = c0.w * c0.w / (n0.w + EPSc);
            p[4] = c1.x * c1.x / (n1.x + EPSc); p[5] = c1.y * c1.y / (n1.y + EPSc);
            p[6] = c1.z * c1.z / (n1.z + EPSc); p[7] = c1.w * c1.w / (n1.w + EPSc);
            float s = p[0] + p[1] + p[2] + p[3] + p[4] + p[5] + p[6] + p[7];
            float pn = waveReduceSum(s) + EPSc;
            float rpn = 1.0f / pn;
            float cc[8] = {c0.x, c0.y, c0.z, c0.w, c1.x, c1.y, c1.z, c1.w};
#pragma unroll
            for (int j = 0; j < 8; j++) {
                float P = p[j] * rpn;
                kacc += P * __logf((P + EPSc) / (cc[j] + EPSc));
            }
        }
        kacc = waveReduceSum(kacc);
        if (l == 0) red[w] = kacc;
        __syncthreads();
        if (tid == 0)
            atomicAdd(klout, 100.f * (red[0] + red[1] + red[2] + red[3]));
    }
}

extern "C" void kernel_launch(void* const* d_in, const int* in_sizes, int n_in,
                              void* d_out, int out_size, void* d_ws, size_t ws_size,
                              hipStream_t stream) {
    const float* Q = (const float*)d_in[0];
    const float* keys = (const float*)d_in[1];
    const float* conv_w = (const float*)d_in[2];
    const float* lin_w = (const float*)d_in[3];
    const float* lin_b = (const float*)d_in[4];
    const int* mask = (const int*)d_in[5];

    float* out = (float*)d_out;
    float* kl = out + (size_t)Bc * Kc * DOUTc;

    float* ws = (float*)d_ws;
    float* C = ws;                                   // 8,388,608 f
    float* k2 = C + (size_t)Bc * Nc * Kc;            // 4,096 f
    float* cn = k2 + (size_t)Hc * Kc;                // 8,192 f
    float* q2 = cn + (size_t)Bc * Kc;                // 16,384 f
    unsigned short* Qb = (unsigned short*)(q2 + (size_t)Bc * Nc);  // 4,194,304 us
    unsigned short* Kp = Qb + (size_t)Bc * Nc * Fc;                // 1,048,576 us
    unsigned short* Ctp = Kp + (size_t)Hc * Kc * Fc;               // 8,388,608 us
    unsigned short* Qbp = Ctp + (size_t)Bc * Nc * Kc;              // 4,194,304 us
    unsigned short* Wp = Qbp + (size_t)Bc * Nc * Fc;               // 65,536 us

    prep_all<<<7714, 256, 0, stream>>>(Q, keys, lin_w, Qb, q2, k2, Kp, Qbp, Wp, cn, kl);
    cmfma_kernel<<<Bc * Nc / 32, 256, 0, stream>>>(Qb, Kp, q2, k2, conv_w, mask, C, cn, Ctp);
    vout_kl_kernel<<<1536, 256, 0, stream>>>(Ctp, Qbp, Wp, lin_b, out, C, cn, kl);
}